// Round 9
// baseline (82.162 us; speedup 1.0000x reference)
//
#include <hip/hip_runtime.h>
#include <math.h>

#define NPRED 16384
#define NGT   32768
#define BETA  0.45f
#define GAMMA 0.45f

#define BLOCK 256
#define PPT   8                                // preds per thread (16 spills: R6/R8)
#define PRED_PER_BLOCK (BLOCK * PPT)           // 2048
#define PRED_CHUNKS (NPRED / PRED_PER_BLOCK)   // 8
#define SLAB  256                              // gt rows per block (== BLOCK)
#define NPAIR (SLAB / 2)                       // 128 row-pairs
#define NSLAB (NGT / SLAB)                     // 128

typedef float f4 __attribute__((ext_vector_type(4)));
typedef float f2 __attribute__((ext_vector_type(2)));

// ---------------------------------------------------------------------------
// nn: packed-fp32 min-distance. LDS holds TRANSPOSED row-pairs:
//   lds[rp*8 + {0,1}] = -2*{gx_even, gx_odd}, +{2,3} = -2*gy, +{4,5} = -2*gz,
//   +{6,7} = |g|^2.  Per pred per row-pair:
//     d(pair) = pk_fma(px2, Gx, pk_fma(py2, Gy, pk_fma(pz2, Gz, Gw)))
//     v_min3_f32(kmin, d.x, d.y)
//   = 4 instr / 2 pairs = 2.0 VALU ops/pair; per-half fmaf chain is
//   bit-identical to the rescan's scalar chain.
// 4-deep buffer rotation: each ds_read issued ~3 STEPs (~192 cyc) before use.
// Cross-slab merge: u64 atomicMin on sortable(dmin)<<32 | slab_id.
// ---------------------------------------------------------------------------
__global__ __launch_bounds__(BLOCK, 4) void nn_kernel(
    const float* __restrict__ pred_feat,
    const float* __restrict__ gt_data,
    unsigned long long* __restrict__ packed,
    float4* __restrict__ hglob)
{
    __shared__ float lds[(NPAIR + 3) * 8];     // 131 pairs * 32 B

    const int chunk   = blockIdx.x;
    const int slab    = blockIdx.y;
    const int gt_base = slab * SLAB;
    const int t       = threadIdx.x;

    {   // stage row t transposed into its pair slot
        const int gj = gt_base + t;
        const float x = gt_data[gj * 6 + 0];
        const float y = gt_data[gj * 6 + 1];
        const float z = gt_data[gj * 6 + 2];
        const float g2 = fmaf(x, x, fmaf(y, y, z * z));
        const int rp = t >> 1, h = t & 1;
        lds[rp * 8 + 0 + h] = -2.0f * x;
        lds[rp * 8 + 2 + h] = -2.0f * y;
        lds[rp * 8 + 4 + h] = -2.0f * z;
        lds[rp * 8 + 6 + h] = g2;
        if (chunk == 0) hglob[gj] = make_float4(-2.0f * x, -2.0f * y, -2.0f * z, g2);
        if (t < 6) {                            // 3 pad pairs: d evaluates to 1e30
            const int rp2 = NPAIR + (t >> 1), h2 = t & 1;
            lds[rp2 * 8 + 0 + h2] = 0.0f;
            lds[rp2 * 8 + 2 + h2] = 0.0f;
            lds[rp2 * 8 + 4 + h2] = 0.0f;
            lds[rp2 * 8 + 6 + h2] = 1e30f;
        }
    }
    __syncthreads();

    f2 px2[PPT], py2[PPT], pz2[PPT];
    float kmin[PPT];
    const int pred_base = chunk * PRED_PER_BLOCK + t;
#pragma unroll
    for (int p = 0; p < PPT; ++p) {
        const int i = pred_base + p * BLOCK;
        const float x = pred_feat[i * 6 + 0];
        const float y = pred_feat[i * 6 + 1];
        const float z = pred_feat[i * 6 + 2];
        px2[p] = (f2){x, x}; py2[p] = (f2){y, y}; pz2[p] = (f2){z, z};
        kmin[p] = 1e30f;
    }

#define LOADU(Uxy, Uzw, rp)                                                   \
    { const f4* q_ = (const f4*)&lds[(rp) * 8]; Uxy = q_[0]; Uzw = q_[1]; }

#define STEP(Uxy, Uzw)                                                        \
    { const f2 Gx = Uxy.lo, Gy = Uxy.hi, Gz = Uzw.lo, Gw = Uzw.hi;            \
      _Pragma("unroll")                                                       \
      for (int p = 0; p < PPT; ++p) {                                         \
          f2 d;                                                               \
          asm("v_pk_fma_f32 %0, %1, %2, %3"                                   \
              : "=v"(d) : "v"(pz2[p]), "v"(Gz), "v"(Gw));                     \
          asm("v_pk_fma_f32 %0, %1, %2, %0"                                   \
              : "+v"(d) : "v"(py2[p]), "v"(Gy));                              \
          asm("v_pk_fma_f32 %0, %1, %2, %0"                                   \
              : "+v"(d) : "v"(px2[p]), "v"(Gx));                              \
          asm("v_min3_f32 %0, %0, %1, %2"                                     \
              : "+v"(kmin[p]) : "v"(d.x), "v"(d.y));                          \
      } }

    f4 Axy, Azw, Bxy, Bzw, Cxy, Czw, Dxy, Dzw;
    LOADU(Axy, Azw, 0) LOADU(Bxy, Bzw, 1) LOADU(Cxy, Czw, 2)
#pragma unroll 1
    for (int rp = 0; rp < NPAIR; rp += 4) {
        LOADU(Dxy, Dzw, rp + 3) STEP(Axy, Azw)
        LOADU(Axy, Azw, rp + 4) STEP(Bxy, Bzw)
        LOADU(Bxy, Bzw, rp + 5) STEP(Cxy, Czw)
        LOADU(Cxy, Czw, rp + 6) STEP(Dxy, Dzw)   // last iter loads hit pad pairs
    }
#undef STEP
#undef LOADU

#pragma unroll
    for (int p = 0; p < PPT; ++p) {
        const int i = pred_base + p * BLOCK;
        const unsigned int bits = __float_as_uint(kmin[p]);
        const unsigned int key  = (bits & 0x80000000u) ? ~bits : (bits | 0x80000000u);
        const unsigned long long pk =
            ((unsigned long long)key << 32) | (unsigned int)slab;
        atomicMin(&packed[i], pk);
    }
}

// ---------------------------------------------------------------------------
// rescan + finalize, wave-cooperative: one wave per pred, coalesced slab scan,
// first match via ballot+ffsll (bit-identical fmaf chain). 2 preds/wave for
// more TLP (latency-bound gather).
// ---------------------------------------------------------------------------
#define RES_PREDS_PER_WAVE 2
#define RES_PREDS_PER_BLOCK (4 * RES_PREDS_PER_WAVE)   // 8
#define RES_BLOCKS (NPRED / RES_PREDS_PER_BLOCK)       // 2048

__global__ __launch_bounds__(BLOCK) void rescan_kernel(
    const float* __restrict__ pred_feat,
    const float* __restrict__ gt_data,
    const float4* __restrict__ hglob,
    const float* __restrict__ Rm,
    const float* __restrict__ tv,
    const float* __restrict__ sv,
    const unsigned long long* __restrict__ packed,
    float* __restrict__ out)
{
    __shared__ float wsum[4];
    const int wave = threadIdx.x >> 6;
    const int lane = threadIdx.x & 63;

    float csum = 0.0f;
#pragma unroll
    for (int q = 0; q < RES_PREDS_PER_WAVE; ++q) {
        const int i = blockIdx.x * RES_PREDS_PER_BLOCK + wave * RES_PREDS_PER_WAVE + q;

        const unsigned long long pk = packed[i];
        const unsigned int key  = (unsigned int)(pk >> 32);
        const unsigned int slab = (unsigned int)(pk & 0xFFFFFFFFu);
        const unsigned int tbits = (key & 0x80000000u) ? (key ^ 0x80000000u) : ~key;
        const int gt_base = (int)slab * SLAB;

        const float px = pred_feat[i * 6 + 0];
        const float py = pred_feat[i * 6 + 1];
        const float pz = pred_feat[i * 6 + 2];

        int jfound = 0;
        bool done = false;
#pragma unroll
        for (int k = 0; k < SLAB / 64; ++k) {
            const float4 g = hglob[gt_base + k * 64 + lane];
            const float d = fmaf(px, g.x, fmaf(py, g.y, fmaf(pz, g.z, g.w)));
            const unsigned long long m = __ballot(__float_as_uint(d) == tbits);
            if (!done && m) {
                jfound = k * 64 + (__ffsll((unsigned long long)m) - 1);
                done = true;
            }
        }
        const int idx = gt_base + jfound;

        if (lane == 0) {
            const float nx = pred_feat[i * 6 + 3];
            const float ny = pred_feat[i * 6 + 4];
            const float nz = pred_feat[i * 6 + 5];
            const float gx = gt_data[idx * 6 + 3];
            const float gy = gt_data[idx * 6 + 4];
            const float gz = gt_data[idx * 6 + 5];
            const float pn = fmaxf(sqrtf(fmaf(nx, nx, fmaf(ny, ny, nz * nz))), 1e-12f);
            const float gn = fmaxf(sqrtf(fmaf(gx, gx, fmaf(gy, gy, gz * gz))), 1e-12f);
            const float cosv = fmaf(nx, gx, fmaf(ny, gy, nz * gz)) / (pn * gn);
            csum += 1.0f - cosv;
        }
    }

    if (lane == 0) wsum[wave] = csum;
    __syncthreads();

    if (threadIdx.x == 0) {
        float s = wsum[0] + wsum[1] + wsum[2] + wsum[3];
        atomicAdd(out, s * (GAMMA / (float)NPRED));
        if (blockIdx.x == 0) {
            float rs = 0.0f;
#pragma unroll
            for (int k = 0; k < 9; ++k) {
                const float v = Rm[k] - ((k % 4 == 0) ? 1.0f : 0.0f);
                rs = fmaf(v, v, rs);
            }
            const float rot = sqrtf(rs);
            const float tr  = sqrtf(fmaf(tv[0], tv[0], fmaf(tv[1], tv[1], tv[2] * tv[2])));
            const float sc  = (sv[0] - 1.0f) * (sv[0] - 1.0f);
            atomicAdd(out, BETA * (rot + tr + sc));
        }
    }
}

extern "C" void kernel_launch(void* const* d_in, const int* in_sizes, int n_in,
                              void* d_out, int out_size, void* d_ws, size_t ws_size,
                              hipStream_t stream)
{
    const float* pred = (const float*)d_in[0];
    const float* gt   = (const float*)d_in[1];
    const float* Rm   = (const float*)d_in[2];
    const float* tv   = (const float*)d_in[3];
    const float* sv   = (const float*)d_in[4];
    float* out = (float*)d_out;

    unsigned long long* packed = (unsigned long long*)d_ws;                      // 128 KB
    float4* hglob = (float4*)((char*)d_ws + NPRED * sizeof(unsigned long long)); // 512 KB

    hipMemsetAsync(packed, 0xFF, NPRED * sizeof(unsigned long long), stream);
    hipMemsetAsync(out, 0, sizeof(float), stream);

    dim3 grid(PRED_CHUNKS, NSLAB);
    nn_kernel<<<grid, BLOCK, 0, stream>>>(pred, gt, packed, hglob);
    rescan_kernel<<<RES_BLOCKS, BLOCK, 0, stream>>>(pred, gt, hglob, Rm, tv, sv,
                                                    packed, out);
}

// Round 10
// 50.016 us; speedup vs baseline: 1.6427x; 1.6427x over previous
//
#include <hip/hip_runtime.h>
#include <math.h>

#define NPRED 16384
#define NGT   32768
#define BETA  0.45f
#define GAMMA 0.45f

#define NTILE (NGT / 32)          // 1024 gt tiles of 32 rows
#define GSPLIT 16                 // gt splits (parallelism axis)
#define TPS (NTILE / GSPLIT)      // 64 tiles per split
#define PB  128                   // preds per nn block (4 waves x 32)
#define NN_BX (NPRED / PB)        // 128
#define RESB (NPRED / 8)          // 2048 rescan blocks (8 preds each)

typedef float f32x16 __attribute__((ext_vector_type(16)));
typedef short short8 __attribute__((ext_vector_type(8)));

__device__ __forceinline__ unsigned bf16h(float f) {          // RNE f32->bf16
    unsigned u = __float_as_uint(f);
    return (u + 0x7FFFu + ((u >> 16) & 1u)) >> 16;
}
__device__ __forceinline__ float bf16f(unsigned h) { return __uint_as_float(h << 16); }
__device__ __forceinline__ unsigned pk2(unsigned lo, unsigned hi) { return lo | (hi << 16); }
__device__ __forceinline__ float min3f(float a, float b, float c) {
    float d; asm("v_min3_f32 %0, %1, %2, %3" : "=v"(d) : "v"(a), "v"(b), "v"(c)); return d;
}

// ---------------------------------------------------------------------------
// prep: build MFMA A-fragments per gt row.  K-slot plan (one MFMA = d directly):
//   A k0..7  (lanes<32):  [xh,xh,xl,xl, yh,yh,yl,yl]      (gt coords, split)
//   A k8..15 (lanes>=32): [zh,zh,zl,zl, g2h,g2l, 0,0]
//   B k0..7:  [mxh,mxl,mxh,mxl, myh,myl,myh,myl]          (m = -2*pred, split)
//   B k8..15: [mzh,mzl,mzh,mzl, 1,1, 0,0]
// => acc[i][j] = gj^2 - 2 p_i . g_j  (+ ~2^-16 rel err).  Every K-pair has one
// duplicated operand so u16 pack order within a pair cannot matter.
// AF[tile*64 + half*32 + r] = uint4 frag for row r, half = lane>>5.
// ---------------------------------------------------------------------------
__global__ __launch_bounds__(256) void prep_kernel(
    const float* __restrict__ gt, uint4* __restrict__ AF)
{
    const int j = blockIdx.x * 256 + threadIdx.x;
    if (j >= NGT) return;
    const float x = gt[j * 6 + 0], y = gt[j * 6 + 1], z = gt[j * 6 + 2];
    const float g2 = fmaf(x, x, fmaf(y, y, z * z));
    const unsigned xh = bf16h(x),  yh = bf16h(y),  zh = bf16h(z),  gh = bf16h(g2);
    const unsigned xl = bf16h(x - bf16f(xh)), yl = bf16h(y - bf16f(yh));
    const unsigned zl = bf16h(z - bf16f(zh)), gl = bf16h(g2 - bf16f(gh));
    const int tile = j >> 5, r = j & 31;
    AF[tile * 64 + r]      = make_uint4(pk2(xh, xh), pk2(xl, xl), pk2(yh, yh), pk2(yl, yl));
    AF[tile * 64 + 32 + r] = make_uint4(pk2(zh, zh), pk2(zl, zl), pk2(gh, gl), 0u);
}

// ---------------------------------------------------------------------------
// nn: one MFMA per (wave, 32-row gt tile) -> 1024 d values; per-lane min3 tree
// over the 16 acc values (col = lane&31 = pred [m74/m101]), track (kmin, tile).
// End: cross-half merge (lane l <-> l+32 hold complementary rows), then
// u64 atomicMin on sortable(kmin)<<32 | tile  (ties -> lower tile id).
// ---------------------------------------------------------------------------
__global__ __launch_bounds__(256) void nn_kernel(
    const float* __restrict__ pred,
    const uint4* __restrict__ AF,
    unsigned long long* __restrict__ packed)
{
    const int l  = threadIdx.x & 63;
    const int w  = threadIdx.x >> 6;
    const int pi = blockIdx.x * PB + w * 32 + (l & 31);

    // B fragment (loop-invariant): m = -2 * pred coords, bf16 split
    const float x = pred[pi * 6 + 0], y = pred[pi * 6 + 1], zc = pred[pi * 6 + 2];
    const float mx = -2.0f * x, my = -2.0f * y, mz = -2.0f * zc;
    const unsigned xh = bf16h(mx), yh = bf16h(my), zh = bf16h(mz);
    const unsigned xl = bf16h(mx - bf16f(xh)), yl = bf16h(my - bf16f(yh));
    const unsigned zl = bf16h(mz - bf16f(zh));
    const bool hi = l >= 32;
    uint4 bu;
    bu.x = hi ? pk2(zh, zl) : pk2(xh, xl);
    bu.y = bu.x;
    bu.z = hi ? 0x3F803F80u : pk2(yh, yl);   // bf16(1.0) pair for the g^2 slots
    bu.w = hi ? 0u : bu.z;
    const short8 bv = *(const short8*)&bu;
    const f32x16 zero = {0.f,0.f,0.f,0.f,0.f,0.f,0.f,0.f,
                         0.f,0.f,0.f,0.f,0.f,0.f,0.f,0.f};

    float kmin = 1e30f;
    int   tix  = 0;
    const int t0 = blockIdx.y * TPS;
    const uint4* ap = AF + (size_t)t0 * 64 + l;

#pragma unroll 2
    for (int t = 0; t < TPS; ++t) {
        const uint4 au = ap[t * 64];
        const short8 av = *(const short8*)&au;
        const f32x16 acc = __builtin_amdgcn_mfma_f32_32x32x16_bf16(av, bv, zero, 0, 0, 0);
        const float m0 = min3f(acc[0],  acc[1],  acc[2]);
        const float m1 = min3f(acc[3],  acc[4],  acc[5]);
        const float m2 = min3f(acc[6],  acc[7],  acc[8]);
        const float m3 = min3f(acc[9],  acc[10], acc[11]);
        const float m4 = min3f(acc[12], acc[13], acc[14]);
        const float n0 = min3f(m0, m1, m2);
        const float n1 = min3f(m3, m4, acc[15]);
        const float tmin = fminf(n0, n1);
        const bool lt = tmin < kmin;
        kmin = lt ? tmin : kmin;
        tix  = lt ? (t0 + t) : tix;
    }

    // merge the two half-wave row sets (same pred col in lane l and l+32)
    const float ko = __shfl_xor(kmin, 32, 64);
    const int   to = __shfl_xor(tix, 32, 64);
    const bool tk = (ko < kmin) || (ko == kmin && to < tix);
    kmin = tk ? ko : kmin;
    tix  = tk ? to : tix;

    if (l < 32) {
        const unsigned b = __float_as_uint(kmin);
        const unsigned key = (b & 0x80000000u) ? ~b : (b | 0x80000000u);
        atomicMin(&packed[pi], ((unsigned long long)key << 32) | (unsigned)tix);
    }
}

// ---------------------------------------------------------------------------
// rescan: winning 32-row tile per pred, exact-fp32 argmin (first occurrence)
// via 32-lane lexicographic shuffle reduce. 2 preds per wave. Normals cosine.
// Per-block partial sums -> no float atomics anywhere.
// ---------------------------------------------------------------------------
__global__ __launch_bounds__(256) void rescan_kernel(
    const float* __restrict__ pred,
    const float* __restrict__ gt,
    const unsigned long long* __restrict__ packed,
    float* __restrict__ partials)
{
    __shared__ float part[8];
    const int w = threadIdx.x >> 6, l = threadIdx.x & 63;
    const int half = l >> 5, jl = l & 31;
    const int pi = blockIdx.x * 8 + w * 2 + half;

    const unsigned tix = (unsigned)(packed[pi] & 0xFFFFFFFFull);
    const int row = (int)tix * 32 + jl;
    const float gx = gt[row * 6 + 0], gy = gt[row * 6 + 1], gz = gt[row * 6 + 2];
    const float g2 = fmaf(gx, gx, fmaf(gy, gy, gz * gz));
    const float px = pred[pi * 6 + 0], py = pred[pi * 6 + 1], pz = pred[pi * 6 + 2];
    float d = fmaf(px, -2.0f * gx, fmaf(py, -2.0f * gy, fmaf(pz, -2.0f * gz, g2)));
    int jj = jl;
#pragma unroll
    for (int off = 16; off; off >>= 1) {
        const float d2 = __shfl_xor(d, off, 32);
        const int   j2 = __shfl_xor(jj, off, 32);
        const bool t = (d2 < d) || (d2 == d && j2 < jj);
        d  = t ? d2 : d;
        jj = t ? j2 : jj;
    }
    if (jl == 0) {
        const int idx = (int)tix * 32 + jj;
        const float nx = pred[pi * 6 + 3], ny = pred[pi * 6 + 4], nz = pred[pi * 6 + 5];
        const float ax = gt[idx * 6 + 3],  ay = gt[idx * 6 + 4],  az = gt[idx * 6 + 5];
        const float pn = fmaxf(sqrtf(fmaf(nx, nx, fmaf(ny, ny, nz * nz))), 1e-12f);
        const float gn = fmaxf(sqrtf(fmaf(ax, ax, fmaf(ay, ay, az * az))), 1e-12f);
        part[w * 2 + half] = 1.0f - fmaf(nx, ax, fmaf(ny, ay, nz * az)) / (pn * gn);
    }
    __syncthreads();
    if (threadIdx.x == 0) {
        float s = 0.f;
#pragma unroll
        for (int i = 0; i < 8; ++i) s += part[i];
        partials[blockIdx.x] = s;
    }
}

// ---------------------------------------------------------------------------
// final: sum partials + regularizer, single write to out[0].
// ---------------------------------------------------------------------------
__global__ __launch_bounds__(256) void final_kernel(
    const float* __restrict__ partials,
    const float* __restrict__ Rm,
    const float* __restrict__ tv,
    const float* __restrict__ sv,
    float* __restrict__ out)
{
    __shared__ float ws_[4];
    float s = 0.f;
    for (int i = threadIdx.x; i < RESB; i += 256) s += partials[i];
#pragma unroll
    for (int off = 32; off; off >>= 1) s += __shfl_down(s, off, 64);
    if ((threadIdx.x & 63) == 0) ws_[threadIdx.x >> 6] = s;
    __syncthreads();
    if (threadIdx.x == 0) {
        const float t = ws_[0] + ws_[1] + ws_[2] + ws_[3];
        float rs = 0.f;
#pragma unroll
        for (int k = 0; k < 9; ++k) {
            const float v = Rm[k] - ((k % 4 == 0) ? 1.0f : 0.0f);
            rs = fmaf(v, v, rs);
        }
        const float rot = sqrtf(rs);
        const float tr  = sqrtf(fmaf(tv[0], tv[0], fmaf(tv[1], tv[1], tv[2] * tv[2])));
        const float sc  = (sv[0] - 1.0f) * (sv[0] - 1.0f);
        out[0] = GAMMA * t / (float)NPRED + BETA * (rot + tr + sc);
    }
}

extern "C" void kernel_launch(void* const* d_in, const int* in_sizes, int n_in,
                              void* d_out, int out_size, void* d_ws, size_t ws_size,
                              hipStream_t stream)
{
    const float* pred = (const float*)d_in[0];
    const float* gt   = (const float*)d_in[1];
    const float* Rm   = (const float*)d_in[2];
    const float* tv   = (const float*)d_in[3];
    const float* sv   = (const float*)d_in[4];
    float* out = (float*)d_out;

    unsigned long long* packed = (unsigned long long*)d_ws;                 // 128 KB
    uint4* AF       = (uint4*)((char*)d_ws + 131072);                       // 1 MB
    float* partials = (float*)((char*)d_ws + 131072 + 1048576);             // 8 KB

    hipMemsetAsync(packed, 0xFF, NPRED * sizeof(unsigned long long), stream);

    prep_kernel<<<NGT / 256, 256, 0, stream>>>(gt, AF);
    dim3 grid(NN_BX, GSPLIT);
    nn_kernel<<<grid, 256, 0, stream>>>(pred, AF, packed);
    rescan_kernel<<<RESB, 256, 0, stream>>>(pred, gt, packed, partials);
    final_kernel<<<1, 256, 0, stream>>>(partials, Rm, tv, sv, out);
}

// Round 11
// 48.587 us; speedup vs baseline: 1.6910x; 1.0294x over previous
//
#include <hip/hip_runtime.h>
#include <math.h>

#define NPRED 16384
#define NGT   32768
#define BETA  0.45f
#define GAMMA 0.45f

#define NTILE (NGT / 32)          // 1024 gt tiles of 32 rows
#define GSPLIT 16                 // gt splits (parallelism axis)
#define TPS (NTILE / GSPLIT)      // 64 tiles per split
#define PB  128                   // preds per nn block (4 waves x 32)
#define NN_BX (NPRED / PB)        // 128
#define RESB (NPRED / 8)          // 2048 rescan blocks (8 preds each)

typedef float f32x16 __attribute__((ext_vector_type(16)));
typedef short short8 __attribute__((ext_vector_type(8)));

__device__ __forceinline__ unsigned bf16h(float f) {          // RNE f32->bf16
    unsigned u = __float_as_uint(f);
    return (u + 0x7FFFu + ((u >> 16) & 1u)) >> 16;
}
__device__ __forceinline__ float bf16f(unsigned h) { return __uint_as_float(h << 16); }
__device__ __forceinline__ unsigned pk2(unsigned lo, unsigned hi) { return lo | (hi << 16); }
__device__ __forceinline__ float min3f(float a, float b, float c) {
    float d; asm("v_min3_f32 %0, %1, %2, %3" : "=v"(d) : "v"(a), "v"(b), "v"(c)); return d;
}

// ---------------------------------------------------------------------------
// prep: build MFMA A-fragments per gt row + init packed[] (replaces the
// 40us fillBufferAligned hipMemsetAsync - 80% of the R10 graph!).
// K-slot plan (one MFMA = d directly):
//   A k0..7  (lanes<32):  [xh,xh,xl,xl, yh,yh,yl,yl]      (gt coords, split)
//   A k8..15 (lanes>=32): [zh,zh,zl,zl, g2h,g2l, 0,0]
//   B k0..7:  [mxh,mxl,mxh,mxl, myh,myl,myh,myl]          (m = -2*pred, split)
//   B k8..15: [mzh,mzl,mzh,mzl, 1,1, 0,0]
// => acc[i][j] = gj^2 - 2 p_i . g_j  (+ ~2^-16 rel err).  Every K-pair has one
// duplicated operand so u16 pack order within a pair cannot matter.
// AF[tile*64 + half*32 + r] = uint4 frag for row r, half = lane>>5.
// ---------------------------------------------------------------------------
__global__ __launch_bounds__(256) void prep_kernel(
    const float* __restrict__ gt, uint4* __restrict__ AF,
    unsigned long long* __restrict__ packed)
{
    const int j = blockIdx.x * 256 + threadIdx.x;
    if (j >= NGT) return;
    if (j < NPRED) packed[j] = 0xFFFFFFFFFFFFFFFFull;   // stream-ordered before nn
    const float x = gt[j * 6 + 0], y = gt[j * 6 + 1], z = gt[j * 6 + 2];
    const float g2 = fmaf(x, x, fmaf(y, y, z * z));
    const unsigned xh = bf16h(x),  yh = bf16h(y),  zh = bf16h(z),  gh = bf16h(g2);
    const unsigned xl = bf16h(x - bf16f(xh)), yl = bf16h(y - bf16f(yh));
    const unsigned zl = bf16h(z - bf16f(zh)), gl = bf16h(g2 - bf16f(gh));
    const int tile = j >> 5, r = j & 31;
    AF[tile * 64 + r]      = make_uint4(pk2(xh, xh), pk2(xl, xl), pk2(yh, yh), pk2(yl, yl));
    AF[tile * 64 + 32 + r] = make_uint4(pk2(zh, zh), pk2(zl, zl), pk2(gh, gl), 0u);
}

// ---------------------------------------------------------------------------
// nn: one MFMA per (wave, 32-row gt tile) -> 1024 d values; per-lane min3 tree
// over the 16 acc values (col = lane&31 = pred [m74/m101]), track (kmin, tile).
// End: cross-half merge (lane l <-> l+32 hold complementary rows), then
// u64 atomicMin on sortable(kmin)<<32 | tile  (ties -> lower tile id).
// ---------------------------------------------------------------------------
__global__ __launch_bounds__(256) void nn_kernel(
    const float* __restrict__ pred,
    const uint4* __restrict__ AF,
    unsigned long long* __restrict__ packed)
{
    const int l  = threadIdx.x & 63;
    const int w  = threadIdx.x >> 6;
    const int pi = blockIdx.x * PB + w * 32 + (l & 31);

    // B fragment (loop-invariant): m = -2 * pred coords, bf16 split
    const float x = pred[pi * 6 + 0], y = pred[pi * 6 + 1], zc = pred[pi * 6 + 2];
    const float mx = -2.0f * x, my = -2.0f * y, mz = -2.0f * zc;
    const unsigned xh = bf16h(mx), yh = bf16h(my), zh = bf16h(mz);
    const unsigned xl = bf16h(mx - bf16f(xh)), yl = bf16h(my - bf16f(yh));
    const unsigned zl = bf16h(mz - bf16f(zh));
    const bool hi = l >= 32;
    uint4 bu;
    bu.x = hi ? pk2(zh, zl) : pk2(xh, xl);
    bu.y = bu.x;
    bu.z = hi ? 0x3F803F80u : pk2(yh, yl);   // bf16(1.0) pair for the g^2 slots
    bu.w = hi ? 0u : bu.z;
    const short8 bv = *(const short8*)&bu;
    const f32x16 zero = {0.f,0.f,0.f,0.f,0.f,0.f,0.f,0.f,
                         0.f,0.f,0.f,0.f,0.f,0.f,0.f,0.f};

    float kmin = 1e30f;
    int   tix  = 0;
    const int t0 = blockIdx.y * TPS;
    const uint4* ap = AF + (size_t)t0 * 64 + l;

#pragma unroll 2
    for (int t = 0; t < TPS; ++t) {
        const uint4 au = ap[t * 64];
        const short8 av = *(const short8*)&au;
        const f32x16 acc = __builtin_amdgcn_mfma_f32_32x32x16_bf16(av, bv, zero, 0, 0, 0);
        const float m0 = min3f(acc[0],  acc[1],  acc[2]);
        const float m1 = min3f(acc[3],  acc[4],  acc[5]);
        const float m2 = min3f(acc[6],  acc[7],  acc[8]);
        const float m3 = min3f(acc[9],  acc[10], acc[11]);
        const float m4 = min3f(acc[12], acc[13], acc[14]);
        const float n0 = min3f(m0, m1, m2);
        const float n1 = min3f(m3, m4, acc[15]);
        const float tmin = fminf(n0, n1);
        const bool lt = tmin < kmin;
        kmin = lt ? tmin : kmin;
        tix  = lt ? (t0 + t) : tix;
    }

    // merge the two half-wave row sets (same pred col in lane l and l+32)
    const float ko = __shfl_xor(kmin, 32, 64);
    const int   to = __shfl_xor(tix, 32, 64);
    const bool tk = (ko < kmin) || (ko == kmin && to < tix);
    kmin = tk ? ko : kmin;
    tix  = tk ? to : tix;

    if (l < 32) {
        const unsigned b = __float_as_uint(kmin);
        const unsigned key = (b & 0x80000000u) ? ~b : (b | 0x80000000u);
        atomicMin(&packed[pi], ((unsigned long long)key << 32) | (unsigned)tix);
    }
}

// ---------------------------------------------------------------------------
// rescan: winning 32-row tile per pred, exact-fp32 argmin (first occurrence)
// via 32-lane lexicographic shuffle reduce. 2 preds per wave. Normals cosine.
// Per-block partial sums -> no float atomics anywhere.
// ---------------------------------------------------------------------------
__global__ __launch_bounds__(256) void rescan_kernel(
    const float* __restrict__ pred,
    const float* __restrict__ gt,
    const unsigned long long* __restrict__ packed,
    float* __restrict__ partials)
{
    __shared__ float part[8];
    const int w = threadIdx.x >> 6, l = threadIdx.x & 63;
    const int half = l >> 5, jl = l & 31;
    const int pi = blockIdx.x * 8 + w * 2 + half;

    const unsigned tix = (unsigned)(packed[pi] & 0xFFFFFFFFull);
    const int row = (int)tix * 32 + jl;
    const float gx = gt[row * 6 + 0], gy = gt[row * 6 + 1], gz = gt[row * 6 + 2];
    const float g2 = fmaf(gx, gx, fmaf(gy, gy, gz * gz));
    const float px = pred[pi * 6 + 0], py = pred[pi * 6 + 1], pz = pred[pi * 6 + 2];
    float d = fmaf(px, -2.0f * gx, fmaf(py, -2.0f * gy, fmaf(pz, -2.0f * gz, g2)));
    int jj = jl;
#pragma unroll
    for (int off = 16; off; off >>= 1) {
        const float d2 = __shfl_xor(d, off, 32);
        const int   j2 = __shfl_xor(jj, off, 32);
        const bool t = (d2 < d) || (d2 == d && j2 < jj);
        d  = t ? d2 : d;
        jj = t ? j2 : jj;
    }
    if (jl == 0) {
        const int idx = (int)tix * 32 + jj;
        const float nx = pred[pi * 6 + 3], ny = pred[pi * 6 + 4], nz = pred[pi * 6 + 5];
        const float ax = gt[idx * 6 + 3],  ay = gt[idx * 6 + 4],  az = gt[idx * 6 + 5];
        const float pn = fmaxf(sqrtf(fmaf(nx, nx, fmaf(ny, ny, nz * nz))), 1e-12f);
        const float gn = fmaxf(sqrtf(fmaf(ax, ax, fmaf(ay, ay, az * az))), 1e-12f);
        part[w * 2 + half] = 1.0f - fmaf(nx, ax, fmaf(ny, ay, nz * az)) / (pn * gn);
    }
    __syncthreads();
    if (threadIdx.x == 0) {
        float s = 0.f;
#pragma unroll
        for (int i = 0; i < 8; ++i) s += part[i];
        partials[blockIdx.x] = s;
    }
}

// ---------------------------------------------------------------------------
// final: sum partials + regularizer, single write to out[0].
// ---------------------------------------------------------------------------
__global__ __launch_bounds__(256) void final_kernel(
    const float* __restrict__ partials,
    const float* __restrict__ Rm,
    const float* __restrict__ tv,
    const float* __restrict__ sv,
    float* __restrict__ out)
{
    __shared__ float ws_[4];
    float s = 0.f;
    for (int i = threadIdx.x; i < RESB; i += 256) s += partials[i];
#pragma unroll
    for (int off = 32; off; off >>= 1) s += __shfl_down(s, off, 64);
    if ((threadIdx.x & 63) == 0) ws_[threadIdx.x >> 6] = s;
    __syncthreads();
    if (threadIdx.x == 0) {
        const float t = ws_[0] + ws_[1] + ws_[2] + ws_[3];
        float rs = 0.f;
#pragma unroll
        for (int k = 0; k < 9; ++k) {
            const float v = Rm[k] - ((k % 4 == 0) ? 1.0f : 0.0f);
            rs = fmaf(v, v, rs);
        }
        const float rot = sqrtf(rs);
        const float tr  = sqrtf(fmaf(tv[0], tv[0], fmaf(tv[1], tv[1], tv[2] * tv[2])));
        const float sc  = (sv[0] - 1.0f) * (sv[0] - 1.0f);
        out[0] = GAMMA * t / (float)NPRED + BETA * (rot + tr + sc);
    }
}

extern "C" void kernel_launch(void* const* d_in, const int* in_sizes, int n_in,
                              void* d_out, int out_size, void* d_ws, size_t ws_size,
                              hipStream_t stream)
{
    const float* pred = (const float*)d_in[0];
    const float* gt   = (const float*)d_in[1];
    const float* Rm   = (const float*)d_in[2];
    const float* tv   = (const float*)d_in[3];
    const float* sv   = (const float*)d_in[4];
    float* out = (float*)d_out;

    unsigned long long* packed = (unsigned long long*)d_ws;                 // 128 KB
    uint4* AF       = (uint4*)((char*)d_ws + 131072);                       // 1 MB
    float* partials = (float*)((char*)d_ws + 131072 + 1048576);             // 8 KB

    prep_kernel<<<NGT / 256, 256, 0, stream>>>(gt, AF, packed);
    dim3 grid(NN_BX, GSPLIT);
    nn_kernel<<<grid, 256, 0, stream>>>(pred, AF, packed);
    rescan_kernel<<<RESB, 256, 0, stream>>>(pred, gt, packed, partials);
    final_kernel<<<1, 256, 0, stream>>>(partials, Rm, tv, sv, out);
}

// Round 12
// 42.598 us; speedup vs baseline: 1.9288x; 1.1406x over previous
//
#include <hip/hip_runtime.h>
#include <math.h>

#define NPRED 16384
#define NGT   32768
#define BETA  0.45f
#define GAMMA 0.45f

#define GSPLIT 32                 // gt splits (== lanes in the rescan reduce)
#define NTILE  (NGT / 32)         // 1024 tiles of 32 gt rows
#define TPS    (NTILE / GSPLIT)   // 32 tiles per nn block
#define PB     256                // preds per nn block (4 waves x 64)
#define NN_BX  (NPRED / PB)       // 64
#define RESB   (NPRED / 8)        // 2048 rescan blocks (8 preds each)

typedef float f32x16 __attribute__((ext_vector_type(16)));
typedef short short8 __attribute__((ext_vector_type(8)));

__device__ __forceinline__ unsigned bf16h(float f) {          // RNE f32->bf16
    unsigned u = __float_as_uint(f);
    return (u + 0x7FFFu + ((u >> 16) & 1u)) >> 16;
}
__device__ __forceinline__ float bf16f(unsigned h) { return __uint_as_float(h << 16); }
__device__ __forceinline__ unsigned pk2(unsigned lo, unsigned hi) { return lo | (hi << 16); }
__device__ __forceinline__ float min3f(float a, float b, float c) {
    float d; asm("v_min3_f32 %0, %1, %2, %3" : "=v"(d) : "v"(a), "v"(b), "v"(c)); return d;
}

// ---------------------------------------------------------------------------
// nn (fused prep): each block stages its 32 gt tiles as split-bf16 MFMA
// A-fragments in LDS (32 KB), then 4 waves x 2 pred-groups scan them.
// K-slot plan (verified exact by R10/R11 absmax=0.0):
//   A row j:  k0..7  = [xh,xh,xl,xl, yh,yh,yl,yl]   k8..15 = [zh,zh,zl,zl, g2h,g2l,0,0]
//   B col i:  k0..7  = [mxh,mxl,mxh,mxl, myh,myl,myh,myl]  k8..15 = [mzh,mzl,mzh,mzl,1,1,0,0]
// => acc[j][i] = g_j^2 - 2 p_i . g_j.  C col = lane&31 [m74/m101].
// Per-split result written WITHOUT atomics: packed2[split*NPRED + pred] =
// sortable(kmin)<<32 | tile  (u64 compare == lexicographic (d, tile)).
// ---------------------------------------------------------------------------
__global__ __launch_bounds__(256) void nn_kernel(
    const float* __restrict__ pred,
    const float* __restrict__ gt,
    unsigned long long* __restrict__ packed2)
{
    __shared__ uint4 AF[TPS * 64];                      // 32 KB

    const int l  = threadIdx.x & 63;
    const int w  = threadIdx.x >> 6;
    const int by = blockIdx.y;

    // ---- stage rows [by*1024, +1024) as A-fragments into LDS
#pragma unroll
    for (int k = 0; k < 4; ++k) {
        const int lrow = threadIdx.x + k * 256;         // 0..1023
        const int j = by * (TPS * 32) + lrow;
        const float x = gt[j * 6 + 0], y = gt[j * 6 + 1], z = gt[j * 6 + 2];
        const float g2 = fmaf(x, x, fmaf(y, y, z * z));
        const unsigned xh = bf16h(x),  yh = bf16h(y),  zh = bf16h(z),  gh = bf16h(g2);
        const unsigned xl = bf16h(x - bf16f(xh)), yl = bf16h(y - bf16f(yh));
        const unsigned zl = bf16h(z - bf16f(zh)), gl = bf16h(g2 - bf16f(gh));
        const int tl = lrow >> 5, r = lrow & 31;
        AF[tl * 64 + r]      = make_uint4(pk2(xh, xh), pk2(xl, xl), pk2(yh, yh), pk2(yl, yl));
        AF[tl * 64 + 32 + r] = make_uint4(pk2(zh, zl) & 0u | pk2(zh, zh), pk2(zl, zl), pk2(gh, gl), 0u);
    }
    __syncthreads();

    // ---- two B fragments (pred groups c and c+32)
    const int pbase = blockIdx.x * PB + w * 64;
    const int c     = l & 31;
    const bool hi   = l >= 32;
    uint4 bu0, bu1;
    {
        const int pi = pbase + c;
        const float x = pred[pi * 6 + 0], y = pred[pi * 6 + 1], zc = pred[pi * 6 + 2];
        const float mx = -2.0f * x, my = -2.0f * y, mz = -2.0f * zc;
        const unsigned xh = bf16h(mx), yh = bf16h(my), zh = bf16h(mz);
        const unsigned xl = bf16h(mx - bf16f(xh)), yl = bf16h(my - bf16f(yh));
        const unsigned zl = bf16h(mz - bf16f(zh));
        bu0.x = hi ? pk2(zh, zl) : pk2(xh, xl);
        bu0.y = bu0.x;
        bu0.z = hi ? 0x3F803F80u : pk2(yh, yl);
        bu0.w = hi ? 0u : bu0.z;
    }
    {
        const int pi = pbase + 32 + c;
        const float x = pred[pi * 6 + 0], y = pred[pi * 6 + 1], zc = pred[pi * 6 + 2];
        const float mx = -2.0f * x, my = -2.0f * y, mz = -2.0f * zc;
        const unsigned xh = bf16h(mx), yh = bf16h(my), zh = bf16h(mz);
        const unsigned xl = bf16h(mx - bf16f(xh)), yl = bf16h(my - bf16f(yh));
        const unsigned zl = bf16h(mz - bf16f(zh));
        bu1.x = hi ? pk2(zh, zl) : pk2(xh, xl);
        bu1.y = bu1.x;
        bu1.z = hi ? 0x3F803F80u : pk2(yh, yl);
        bu1.w = hi ? 0u : bu1.z;
    }
    const short8 bv0 = *(const short8*)&bu0;
    const short8 bv1 = *(const short8*)&bu1;
    const f32x16 zero = {0.f,0.f,0.f,0.f,0.f,0.f,0.f,0.f,
                         0.f,0.f,0.f,0.f,0.f,0.f,0.f,0.f};

    float kmin0 = 1e30f, kmin1 = 1e30f;
    int   tix0  = 0,     tix1  = 0;
    const int t0 = by * TPS;

#pragma unroll 2
    for (int tt = 0; tt < TPS; ++tt) {
        const uint4 au = AF[tt * 64 + l];
        const short8 av = *(const short8*)&au;
        {
            const f32x16 acc = __builtin_amdgcn_mfma_f32_32x32x16_bf16(av, bv0, zero, 0, 0, 0);
            const float m0 = min3f(acc[0],  acc[1],  acc[2]);
            const float m1 = min3f(acc[3],  acc[4],  acc[5]);
            const float m2 = min3f(acc[6],  acc[7],  acc[8]);
            const float m3 = min3f(acc[9],  acc[10], acc[11]);
            const float m4 = min3f(acc[12], acc[13], acc[14]);
            const float tmin = fminf(min3f(m0, m1, m2), min3f(m3, m4, acc[15]));
            const bool lt = tmin < kmin0;
            kmin0 = lt ? tmin : kmin0;
            tix0  = lt ? (t0 + tt) : tix0;
        }
        {
            const f32x16 acc = __builtin_amdgcn_mfma_f32_32x32x16_bf16(av, bv1, zero, 0, 0, 0);
            const float m0 = min3f(acc[0],  acc[1],  acc[2]);
            const float m1 = min3f(acc[3],  acc[4],  acc[5]);
            const float m2 = min3f(acc[6],  acc[7],  acc[8]);
            const float m3 = min3f(acc[9],  acc[10], acc[11]);
            const float m4 = min3f(acc[12], acc[13], acc[14]);
            const float tmin = fminf(min3f(m0, m1, m2), min3f(m3, m4, acc[15]));
            const bool lt = tmin < kmin1;
            kmin1 = lt ? tmin : kmin1;
            tix1  = lt ? (t0 + tt) : tix1;
        }
    }

    // cross-half merge for both groups (lane l <-> l+32 hold complementary rows)
    {
        const float ko = __shfl_xor(kmin0, 32, 64);
        const int   to = __shfl_xor(tix0, 32, 64);
        const bool tk = (ko < kmin0) || (ko == kmin0 && to < tix0);
        kmin0 = tk ? ko : kmin0;  tix0 = tk ? to : tix0;
    }
    {
        const float ko = __shfl_xor(kmin1, 32, 64);
        const int   to = __shfl_xor(tix1, 32, 64);
        const bool tk = (ko < kmin1) || (ko == kmin1 && to < tix1);
        kmin1 = tk ? ko : kmin1;  tix1 = tk ? to : tix1;
    }

    // lane l owns pred pbase + l (group by hi); coalesced u64 store, no atomics
    const float km = hi ? kmin1 : kmin0;
    const int   tx = hi ? tix1  : tix0;
    const unsigned bb  = __float_as_uint(km);
    const unsigned key = (bb & 0x80000000u) ? ~bb : (bb | 0x80000000u);
    packed2[(size_t)by * NPRED + pbase + l] =
        ((unsigned long long)key << 32) | (unsigned)tx;
}

// ---------------------------------------------------------------------------
// rescan: 32 lanes u64-min-reduce the 32 split entries (lex (d, tile) order,
// ties -> lower tile = lower index), then exact-fp32 argmin in the winning
// 32-row tile (first occurrence). 2 preds per wave; per-block partials.
// ---------------------------------------------------------------------------
__global__ __launch_bounds__(256) void rescan_kernel(
    const float* __restrict__ pred,
    const float* __restrict__ gt,
    const unsigned long long* __restrict__ packed2,
    float* __restrict__ partials)
{
    __shared__ float part[8];
    const int w = threadIdx.x >> 6, l = threadIdx.x & 63;
    const int half = l >> 5, jl = l & 31;
    const int pi = blockIdx.x * 8 + w * 2 + half;

    // reduce over the 32 splits (lane jl holds split jl's entry)
    unsigned long long e = packed2[(size_t)jl * NPRED + pi];
#pragma unroll
    for (int off = 16; off; off >>= 1) {
        const unsigned long long e2 = __shfl_xor(e, off, 32);
        e = (e2 < e) ? e2 : e;
    }
    const unsigned tix = (unsigned)(e & 0xFFFFFFFFull);

    const int row = (int)tix * 32 + jl;
    const float gx = gt[row * 6 + 0], gy = gt[row * 6 + 1], gz = gt[row * 6 + 2];
    const float g2 = fmaf(gx, gx, fmaf(gy, gy, gz * gz));
    const float px = pred[pi * 6 + 0], py = pred[pi * 6 + 1], pz = pred[pi * 6 + 2];
    float d = fmaf(px, -2.0f * gx, fmaf(py, -2.0f * gy, fmaf(pz, -2.0f * gz, g2)));
    int jj = jl;
#pragma unroll
    for (int off = 16; off; off >>= 1) {
        const float d2 = __shfl_xor(d, off, 32);
        const int   j2 = __shfl_xor(jj, off, 32);
        const bool t = (d2 < d) || (d2 == d && j2 < jj);
        d  = t ? d2 : d;
        jj = t ? j2 : jj;
    }
    if (jl == 0) {
        const int idx = (int)tix * 32 + jj;
        const float nx = pred[pi * 6 + 3], ny = pred[pi * 6 + 4], nz = pred[pi * 6 + 5];
        const float ax = gt[idx * 6 + 3],  ay = gt[idx * 6 + 4],  az = gt[idx * 6 + 5];
        const float pn = fmaxf(sqrtf(fmaf(nx, nx, fmaf(ny, ny, nz * nz))), 1e-12f);
        const float gn = fmaxf(sqrtf(fmaf(ax, ax, fmaf(ay, ay, az * az))), 1e-12f);
        part[w * 2 + half] = 1.0f - fmaf(nx, ax, fmaf(ny, ay, nz * az)) / (pn * gn);
    }
    __syncthreads();
    if (threadIdx.x == 0) {
        float s = 0.f;
#pragma unroll
        for (int i = 0; i < 8; ++i) s += part[i];
        partials[blockIdx.x] = s;
    }
}

// ---------------------------------------------------------------------------
// final: sum partials + regularizer, single write to out[0].
// ---------------------------------------------------------------------------
__global__ __launch_bounds__(256) void final_kernel(
    const float* __restrict__ partials,
    const float* __restrict__ Rm,
    const float* __restrict__ tv,
    const float* __restrict__ sv,
    float* __restrict__ out)
{
    __shared__ float ws_[4];
    float s = 0.f;
    for (int i = threadIdx.x; i < RESB; i += 256) s += partials[i];
#pragma unroll
    for (int off = 32; off; off >>= 1) s += __shfl_down(s, off, 64);
    if ((threadIdx.x & 63) == 0) ws_[threadIdx.x >> 6] = s;
    __syncthreads();
    if (threadIdx.x == 0) {
        const float t = ws_[0] + ws_[1] + ws_[2] + ws_[3];
        float rs = 0.f;
#pragma unroll
        for (int k = 0; k < 9; ++k) {
            const float v = Rm[k] - ((k % 4 == 0) ? 1.0f : 0.0f);
            rs = fmaf(v, v, rs);
        }
        const float rot = sqrtf(rs);
        const float tr  = sqrtf(fmaf(tv[0], tv[0], fmaf(tv[1], tv[1], tv[2] * tv[2])));
        const float sc  = (sv[0] - 1.0f) * (sv[0] - 1.0f);
        out[0] = GAMMA * t / (float)NPRED + BETA * (rot + tr + sc);
    }
}

extern "C" void kernel_launch(void* const* d_in, const int* in_sizes, int n_in,
                              void* d_out, int out_size, void* d_ws, size_t ws_size,
                              hipStream_t stream)
{
    const float* pred = (const float*)d_in[0];
    const float* gt   = (const float*)d_in[1];
    const float* Rm   = (const float*)d_in[2];
    const float* tv   = (const float*)d_in[3];
    const float* sv   = (const float*)d_in[4];
    float* out = (float*)d_out;

    unsigned long long* packed2 = (unsigned long long*)d_ws;        // 4 MB (fully written)
    float* partials = (float*)((char*)d_ws + (size_t)GSPLIT * NPRED * 8);  // 8 KB

    nn_kernel<<<dim3(NN_BX, GSPLIT), 256, 0, stream>>>(pred, gt, packed2);
    rescan_kernel<<<RESB, 256, 0, stream>>>(pred, gt, packed2, partials);
    final_kernel<<<1, 256, 0, stream>>>(partials, Rm, tv, sv, out);
}